// Round 7
// baseline (74.665 us; speedup 1.0000x reference)
//
#include <hip/hip_runtime.h>
#include <math.h>

typedef short bfx8 __attribute__((ext_vector_type(8)));
typedef short bfx4 __attribute__((ext_vector_type(4)));
typedef float fx4  __attribute__((ext_vector_type(4)));

__device__ __forceinline__ unsigned short f2bf(float f) {
    unsigned int u = __builtin_bit_cast(unsigned int, f);
    u += 0x7FFFu + ((u >> 16) & 1u);        // round-to-nearest-even
    return (unsigned short)(u >> 16);
}
__device__ __forceinline__ float bf2f(unsigned short s) {
    unsigned int u = ((unsigned int)s) << 16;
    return __builtin_bit_cast(float, u);
}

// ---------- Wt prep: wt[192][1024] bf16 = [Wq*(2^-5*log2e); Wk; Wv]^T ----------
__global__ __launch_bounds__(256) void wt_prep(const float* __restrict__ Wq,
                                               const float* __restrict__ Wk,
                                               const float* __restrict__ Wv,
                                               unsigned short* __restrict__ wt)
{
    const int k0  = blockIdx.x * 64;
    const int mat = blockIdx.y;
    const float* W = (mat == 0) ? Wq : ((mat == 1) ? Wk : Wv);
    const float scale = (mat == 0) ? (0.03125f * 1.4426950408889634f) : 1.0f;
    __shared__ unsigned short Ls[64 * 68];
    const int t = threadIdx.x;
    #pragma unroll
    for (int i = 0; i < 4; ++i) {
        int idx4 = t + 256 * i;
        int r = idx4 >> 4, c4 = idx4 & 15;
        float4 v = *(const float4*)&W[(size_t)(k0 + r) * 64 + c4 * 4];
        Ls[r * 68 + c4 * 4 + 0] = f2bf(v.x * scale);
        Ls[r * 68 + c4 * 4 + 1] = f2bf(v.y * scale);
        Ls[r * 68 + c4 * 4 + 2] = f2bf(v.z * scale);
        Ls[r * 68 + c4 * 4 + 3] = f2bf(v.w * scale);
    }
    __syncthreads();
    #pragma unroll
    for (int i = 0; i < 2; ++i) {
        int u = t + 256 * i;
        int n = u >> 3, kc = u & 7;
        bfx8 o;
        #pragma unroll
        for (int j = 0; j < 8; ++j) o[j] = (short)Ls[(kc * 8 + j) * 68 + n];
        *(bfx8*)&wt[(size_t)(mat * 64 + n) * 1024 + k0 + kc * 8] = o;
    }
}

// ---------- QKV: BM=32, grid 512, MFMA bf16, double-buffered ----------
__global__ __launch_bounds__(256) void qkv_mfma(
    const float* __restrict__ x, const unsigned short* __restrict__ wt,
    unsigned short* __restrict__ qb, unsigned short* __restrict__ kb,
    unsigned short* __restrict__ vt)
{
    __shared__ alignas(16) char smem[57344];
    const int t = threadIdx.x;
    const int w = t >> 6, l = t & 63, g = l >> 4, li = l & 15;
    const int m0 = blockIdx.x * 32;
    const int rh  = (w & 1) * 16;
    const int nb0 = (w >> 1) * 6;

    fx4 acc[6];
    #pragma unroll
    for (int i = 0; i < 6; ++i) acc[i] = (fx4){0.f, 0.f, 0.f, 0.f};

    float4 xr[2]; bfx8 wr[6];

#define QKV_LOAD(K0) do { \
    _Pragma("unroll") for (int i_ = 0; i_ < 2; ++i_) { int idx4 = t + 256 * i_; int r_ = idx4 >> 4, c4 = idx4 & 15; \
        xr[i_] = *(const float4*)&x[(size_t)(m0 + r_) * 1024 + (K0) + c4 * 4]; } \
    _Pragma("unroll") for (int i_ = 0; i_ < 6; ++i_) { int idx = t + 256 * i_; int n_ = idx >> 3, c_ = idx & 7; \
        wr[i_] = *(const bfx8*)&wt[(size_t)n_ * 1024 + (K0) + c_ * 8]; } \
} while (0)

#define QKV_STORE(BI) do { \
    char* xb_ = smem + (BI) * 4096; \
    char* wb_ = smem + 8192 + (BI) * 24576; \
    _Pragma("unroll") for (int i_ = 0; i_ < 2; ++i_) { int idx4 = t + 256 * i_; int r_ = idx4 >> 4, c4 = idx4 & 15; \
        bfx4 o_; o_[0] = (short)f2bf(xr[i_].x); o_[1] = (short)f2bf(xr[i_].y); \
        o_[2] = (short)f2bf(xr[i_].z); o_[3] = (short)f2bf(xr[i_].w); \
        *(bfx4*)(xb_ + ((r_ * 128 + c4 * 8) ^ ((r_ & 7) << 4))) = o_; } \
    _Pragma("unroll") for (int i_ = 0; i_ < 6; ++i_) { int idx = t + 256 * i_; int n_ = idx >> 3, c_ = idx & 7; \
        *(bfx8*)(wb_ + ((n_ * 128 + c_ * 16) ^ ((n_ & 7) << 4))) = wr[i_]; } \
} while (0)

    QKV_LOAD(0); QKV_STORE(0);
    __syncthreads();

    for (int ch = 0; ch < 16; ++ch) {
        if (ch + 1 < 16) QKV_LOAD((ch + 1) * 64);
        if (ch) __syncthreads();
        char* xb = smem + (ch & 1) * 4096;
        char* wb = smem + 8192 + (ch & 1) * 24576;
        const int arow = rh + li;
        #pragma unroll
        for (int kk = 0; kk < 2; ++kk) {
            bfx8 af = *(bfx8*)(xb + ((arow * 128 + kk * 64 + g * 16) ^ ((arow & 7) << 4)));
            #pragma unroll
            for (int nb = 0; nb < 6; ++nb) {
                int nrow = (nb0 + nb) * 16 + li;
                bfx8 bf = *(bfx8*)(wb + ((nrow * 128 + kk * 64 + g * 16) ^ ((nrow & 7) << 4)));
                acc[nb] = __builtin_amdgcn_mfma_f32_16x16x32_bf16(af, bf, acc[nb], 0, 0, 0);
            }
        }
        if (ch + 1 < 16) QKV_STORE((ch + 1) & 1);
    }

    const int mrow = m0 + rh + g * 4;
    #pragma unroll
    for (int nb = 0; nb < 6; ++nb) {
        const int nbg = nb0 + nb;
        if (nbg < 4) {
            #pragma unroll
            for (int r = 0; r < 4; ++r)
                qb[(size_t)(mrow + r) * 64 + nbg * 16 + li] = f2bf(acc[nb][r]);
        } else if (nbg < 8) {
            #pragma unroll
            for (int r = 0; r < 4; ++r)
                kb[(size_t)(mrow + r) * 64 + (nbg - 4) * 16 + li] = f2bf(acc[nb][r]);
        }
    }

    __syncthreads();
    unsigned short* Vt = (unsigned short*)smem;      // [64 d][40] padded
    #pragma unroll
    for (int nb = 0; nb < 6; ++nb) {
        const int nbg = nb0 + nb;
        if (nbg >= 8) {
            #pragma unroll
            for (int r = 0; r < 4; ++r)
                Vt[((nbg - 8) * 16 + li) * 40 + rh + g * 4 + r] = f2bf(acc[nb][r]);
        }
    }
    __syncthreads();
    const int bb = m0 >> 12, mt = m0 & 4095;
    {
        int d = t >> 2, c = t & 3;
        *(bfx8*)&vt[((size_t)(bb * 64 + d)) * 4096 + mt + c * 8] = *(bfx8*)&Vt[d * 40 + c * 8];
    }
}

// ---------- attention: q-tile 64, 32q/wave, kv-split segments, partials ----------
// grid 640: bx<384 full segs (8 chunks); bx>=384 last segs (qt desc).
// waves: qsub=w&1 (32q), par=w>>1 (kv half of 128-chunk).
__global__ __launch_bounds__(256) void attn_mfma(
    const unsigned short* __restrict__ qb, const unsigned short* __restrict__ kb,
    const unsigned short* __restrict__ vt,
    unsigned short* __restrict__ pO, float* __restrict__ pml)
{
    __shared__ alignas(16) char smem[73728]; // Q@0 8KB; Kbufs@8192,24576; Vbufs@40960,57344
    const int t = threadIdx.x;
    const int w = t >> 6, l = t & 63, g = l >> 4, li = l & 15;
    const int bx = blockIdx.x;

    int b, qt, seg, kvb, nch;
    if (bx < 384) {
        int j = bx >> 2; b = bx & 3;
        if (j < 48)      { seg = 0; qt = 16 + j; }
        else if (j < 80) { seg = 1; qt = 32 + (j - 48); }
        else             { seg = 2; qt = 48 + (j - 80); }
        kvb = seg * 1024; nch = 8;
    } else {
        int j = (bx - 384) >> 2; b = bx & 3;
        qt = 63 - j; seg = qt >> 4; kvb = seg * 1024;
        nch = ((qt & 15) + 2) >> 1;
    }
    const int qbase = qt * 64;
    const int qsub = w & 1, par = w >> 1;
    const int qmax_w = qbase + qsub * 32 + 31;

    // partial slot: base(qt) = 8g(g-1) + r*g + qt
    const int gg = qt >> 4, rr_ = qt & 15;
    const int slot = b * 160 + (8 * gg * (gg - 1) + rr_ * gg + qt) + seg;

    const unsigned short* Qg = qb + (size_t)b * 4096 * 64;
    const unsigned short* Kg = kb + (size_t)b * 4096 * 64;
    const unsigned short* Vg = vt + (size_t)b * 64 * 4096;

    bfx8 krg[4], vrg[4];

#define ATT_LOAD(CB) do { \
    _Pragma("unroll") for (int i_ = 0; i_ < 4; ++i_) { int idx = t + 256 * i_; int r_ = idx >> 3, c_ = idx & 7; \
        krg[i_] = *(const bfx8*)&Kg[(size_t)((CB) + r_) * 64 + c_ * 8]; } \
    _Pragma("unroll") for (int i_ = 0; i_ < 4; ++i_) { int idx = t + 256 * i_; int d_ = idx >> 4, c_ = idx & 15; \
        vrg[i_] = *(const bfx8*)&Vg[(size_t)d_ * 4096 + (CB) + c_ * 8]; } \
} while (0)

#define ATT_STORE(BI) do { \
    char* kb_ = smem + 8192  + (BI) * 16384; \
    char* vb_ = smem + 40960 + (BI) * 16384; \
    _Pragma("unroll") for (int i_ = 0; i_ < 4; ++i_) { int idx = t + 256 * i_; int r_ = idx >> 3, c_ = idx & 7; \
        *(bfx8*)(kb_ + ((r_ * 128 + c_ * 16) ^ ((r_ & 7) << 4))) = krg[i_]; } \
    _Pragma("unroll") for (int i_ = 0; i_ < 4; ++i_) { int idx = t + 256 * i_; int d_ = idx >> 4, c_ = idx & 15; \
        *(bfx8*)(vb_ + ((d_ * 256 + c_ * 16) ^ ((d_ & 7) << 4))) = vrg[i_]; } \
} while (0)

    {   // stage Q tile [64][64]
        #pragma unroll
        for (int i = 0; i < 2; ++i) {
            int idx = t + 256 * i;
            int r2 = idx >> 3, c2 = idx & 7;
            bfx8 qv = *(const bfx8*)&Qg[(size_t)(qbase + r2) * 64 + c2 * 8];
            *(bfx8*)(smem + ((r2 * 128 + c2 * 16) ^ ((r2 & 7) << 4))) = qv;
        }
    }
    ATT_LOAD(kvb); ATT_STORE(0);
    __syncthreads();

    // Q fragments: 2 qfrags x 2 k-halves
    bfx8 qf[2][2];
    #pragma unroll
    for (int f = 0; f < 2; ++f) {
        const int qrow = qsub * 32 + f * 16 + li;
        const int sw = (qrow & 7) << 4;
        qf[f][0] = *(bfx8*)(smem + ((qrow * 128 + g * 16) ^ sw));
        qf[f][1] = *(bfx8*)(smem + ((qrow * 128 + 64 + g * 16) ^ sw));
    }

    fx4 o[4][2];
    #pragma unroll
    for (int i = 0; i < 4; ++i)
        #pragma unroll
        for (int f = 0; f < 2; ++f) o[i][f] = (fx4){0.f, 0.f, 0.f, 0.f};
    float m[2] = {-1e30f, -1e30f}, lsum[2] = {0.f, 0.f};

    for (int ch = 0; ch < nch; ++ch) {
        const int cb = kvb + (ch << 7);
        if (ch + 1 < nch) ATT_LOAD(cb + 128);     // issue early
        char* ks = smem + 8192  + ((ch & 1) ? 16384 : 0);
        char* vs = smem + 40960 + ((ch & 1) ? 16384 : 0);
        const int sub = cb + par * 64;
        if (sub <= qmax_w) {                       // wave-uniform causal skip
            fx4 s[4][2];
            #pragma unroll
            for (int st = 0; st < 4; ++st)
                #pragma unroll
                for (int f = 0; f < 2; ++f) s[st][f] = (fx4){0.f, 0.f, 0.f, 0.f};
            __builtin_amdgcn_s_setprio(1);
            #pragma unroll
            for (int st = 0; st < 4; ++st) {
                const int krow = par * 64 + st * 16 + li;
                const int sw = (krow & 7) << 4;
                bfx8 kf0 = *(bfx8*)(ks + ((krow * 128 + g * 16) ^ sw));
                bfx8 kf1 = *(bfx8*)(ks + ((krow * 128 + 64 + g * 16) ^ sw));
                #pragma unroll
                for (int f = 0; f < 2; ++f) {
                    s[st][f] = __builtin_amdgcn_mfma_f32_16x16x32_bf16(kf0, qf[f][0], s[st][f], 0, 0, 0);
                    s[st][f] = __builtin_amdgcn_mfma_f32_16x16x32_bf16(kf1, qf[f][1], s[st][f], 0, 0, 0);
                }
            }
            __builtin_amdgcn_s_setprio(0);

            bfx8 pf0[2], pf1[2];
            #pragma unroll
            for (int f = 0; f < 2; ++f) {
                const int qmin_f = qbase + qsub * 32 + f * 16;
                float p[16];
                if (sub + 63 > qmin_f) {           // diagonal: apply mask
                    #pragma unroll
                    for (int st = 0; st < 4; ++st)
                        #pragma unroll
                        for (int rr = 0; rr < 4; ++rr) {
                            int kv = sub + st * 16 + 4 * g + rr;
                            p[st * 4 + rr] = (kv <= qmin_f + li) ? s[st][f][rr] : -1e30f;
                        }
                } else {
                    #pragma unroll
                    for (int st = 0; st < 4; ++st)
                        #pragma unroll
                        for (int rr = 0; rr < 4; ++rr) p[st * 4 + rr] = s[st][f][rr];
                }
                float x0 = fmaxf(fmaxf(p[0], p[1]), fmaxf(p[2], p[3]));
                float x1 = fmaxf(fmaxf(p[4], p[5]), fmaxf(p[6], p[7]));
                float x2 = fmaxf(fmaxf(p[8], p[9]), fmaxf(p[10], p[11]));
                float x3 = fmaxf(fmaxf(p[12], p[13]), fmaxf(p[14], p[15]));
                float pmax = fmaxf(fmaxf(x0, x1), fmaxf(x2, x3));
                pmax = fmaxf(pmax, __shfl_xor(pmax, 16));
                pmax = fmaxf(pmax, __shfl_xor(pmax, 32));
                if (__any(pmax > m[f] + 8.f)) {    // defer-max (base-2)
                    float mnew = fmaxf(m[f], pmax);
                    float fac = exp2f(m[f] - mnew);
                    m[f] = mnew; lsum[f] *= fac;
                    #pragma unroll
                    for (int d2 = 0; d2 < 4; ++d2) {
                        o[d2][f][0] *= fac; o[d2][f][1] *= fac;
                        o[d2][f][2] *= fac; o[d2][f][3] *= fac;
                    }
                }
                #pragma unroll
                for (int e = 0; e < 16; ++e) p[e] = exp2f(p[e] - m[f]);
                lsum[f] += (((p[0]+p[1])+(p[2]+p[3])) + ((p[4]+p[5])+(p[6]+p[7])))
                         + (((p[8]+p[9])+(p[10]+p[11])) + ((p[12]+p[13])+(p[14]+p[15])));
                #pragma unroll
                for (int e = 0; e < 8; ++e) {
                    pf0[f][e] = (short)f2bf(p[e]);
                    pf1[f][e] = (short)f2bf(p[8 + e]);
                }
            }

            __builtin_amdgcn_s_setprio(1);
            #pragma unroll
            for (int dblk = 0; dblk < 4; ++dblk) {
                const int dr = dblk * 16 + li;
                const int base = dr * 256 + par * 128;
                const int sw = (dr & 7) << 4;
                bfx4 a0 = *(bfx4*)(vs + ((base + 8 * g)      ^ sw));
                bfx4 a1 = *(bfx4*)(vs + ((base + 32 + 8 * g) ^ sw));
                bfx8 vf0;
                vf0[0] = a0[0]; vf0[1] = a0[1]; vf0[2] = a0[2]; vf0[3] = a0[3];
                vf0[4] = a1[0]; vf0[5] = a1[1]; vf0[6] = a1[2]; vf0[7] = a1[3];
                bfx4 b0 = *(bfx4*)(vs + ((base + 64 + 8 * g) ^ sw));
                bfx4 b1 = *(bfx4*)(vs + ((base + 96 + 8 * g) ^ sw));
                bfx8 vf1;
                vf1[0] = b0[0]; vf1[1] = b0[1]; vf1[2] = b0[2]; vf1[3] = b0[3];
                vf1[4] = b1[0]; vf1[5] = b1[1]; vf1[6] = b1[2]; vf1[7] = b1[3];
                #pragma unroll
                for (int f = 0; f < 2; ++f) {
                    o[dblk][f] = __builtin_amdgcn_mfma_f32_16x16x32_bf16(vf0, pf0[f], o[dblk][f], 0, 0, 0);
                    o[dblk][f] = __builtin_amdgcn_mfma_f32_16x16x32_bf16(vf1, pf1[f], o[dblk][f], 0, 0, 0);
                }
            }
            __builtin_amdgcn_s_setprio(0);
        }
        if (ch + 1 < nch) ATT_STORE((ch + 1) & 1);  // write late (other buffer)
        __syncthreads();
    }

    // ---- epilogue: merge par pairs (w, w+2), write partial (m,l,O) ----
    float* Osh = (float*)smem;                 // [4 waves][32 q][64 d] fp32 = 32KB
    float* msh = (float*)(smem + 32768);       // [4][2][16]
    float* lsh = (float*)(smem + 33280);       // [4][2][4 g][16]
    #pragma unroll
    for (int dblk = 0; dblk < 4; ++dblk)
        #pragma unroll
        for (int f = 0; f < 2; ++f)
            #pragma unroll
            for (int r = 0; r < 4; ++r)
                Osh[(w * 32 + f * 16 + li) * 64 + dblk * 16 + g * 4 + r] = o[dblk][f][r];
    #pragma unroll
    for (int f = 0; f < 2; ++f) {
        if (g == 0) msh[(w * 2 + f) * 16 + li] = m[f];
        lsh[((w * 2 + f) * 4 + g) * 16 + li] = lsum[f];
    }
    __syncthreads();

    {
        const int q = t >> 2, dg = t & 3;
        const int A = q >> 5, Bw = A + 2, fq = (q >> 4) & 1, liq = q & 15, row32 = q & 31;
        const float mA = msh[(A * 2 + fq) * 16 + liq];
        const float mB = msh[(Bw * 2 + fq) * 16 + liq];
        const float lA = lsh[((A * 2 + fq) * 4 + 0) * 16 + liq] + lsh[((A * 2 + fq) * 4 + 1) * 16 + liq]
                       + lsh[((A * 2 + fq) * 4 + 2) * 16 + liq] + lsh[((A * 2 + fq) * 4 + 3) * 16 + liq];
        const float lB = lsh[((Bw * 2 + fq) * 4 + 0) * 16 + liq] + lsh[((Bw * 2 + fq) * 4 + 1) * 16 + liq]
                       + lsh[((Bw * 2 + fq) * 4 + 2) * 16 + liq] + lsh[((Bw * 2 + fq) * 4 + 3) * 16 + liq];
        const float M = fmaxf(mA, mB);
        const float eA = exp2f(mA - M), eB = exp2f(mB - M);
        const float L = lA * eA + lB * eB;
        const float* OA = &Osh[(A * 32 + row32) * 64 + dg * 16];
        const float* OB = &Osh[(Bw * 32 + row32) * 64 + dg * 16];
        bfx8 o1_, o2_;
        #pragma unroll
        for (int j = 0; j < 8; ++j) o1_[j] = (short)f2bf(OA[j] * eA + OB[j] * eB);
        #pragma unroll
        for (int j = 0; j < 8; ++j) o2_[j] = (short)f2bf(OA[8 + j] * eA + OB[8 + j] * eB);
        unsigned short* dst = pO + (size_t)slot * 4096 + q * 64 + dg * 16;
        *(bfx8*)&dst[0] = o1_;
        *(bfx8*)&dst[8] = o2_;
        if (dg == 0) {
            pml[(size_t)slot * 128 + q] = M;
            pml[(size_t)slot * 128 + 64 + q] = L;
        }
    }
}

// ---------- merge: combine up to 4 segment partials, normalize, write out ----------
__global__ __launch_bounds__(256) void attn_merge(
    const unsigned short* __restrict__ pO, const float* __restrict__ pml,
    float* __restrict__ out)
{
    const int b = blockIdx.x & 3, qt = blockIdx.x >> 2;
    const int gg = qt >> 4, rr = qt & 15;
    const int nseg = gg + 1;
    const int slot0 = b * 160 + (8 * gg * (gg - 1) + rr * gg + qt);
    const int t = threadIdx.x;
    const int q = t >> 2, dg = t & 3;

    float ms[4];
    float M = -1e30f;
    #pragma unroll
    for (int s = 0; s < 4; ++s) {
        if (s < nseg) { ms[s] = pml[(size_t)(slot0 + s) * 128 + q]; M = fmaxf(M, ms[s]); }
    }
    float L = 0.f, es[4];
    #pragma unroll
    for (int s = 0; s < 4; ++s) {
        if (s < nseg) {
            es[s] = exp2f(ms[s] - M);
            L += es[s] * pml[(size_t)(slot0 + s) * 128 + 64 + q];
        }
    }
    float acc[16];
    #pragma unroll
    for (int j = 0; j < 16; ++j) acc[j] = 0.f;
    #pragma unroll
    for (int s = 0; s < 4; ++s) {
        if (s < nseg) {
            const unsigned short* src = pO + (size_t)(slot0 + s) * 4096 + q * 64 + dg * 16;
            bfx8 v0 = *(const bfx8*)&src[0];
            bfx8 v1 = *(const bfx8*)&src[8];
            #pragma unroll
            for (int j = 0; j < 8; ++j) acc[j]     += bf2f((unsigned short)v0[j]) * es[s];
            #pragma unroll
            for (int j = 0; j < 8; ++j) acc[8 + j] += bf2f((unsigned short)v1[j]) * es[s];
        }
    }
    const float inv = 1.f / L;
    float* orow = out + ((size_t)b * 4096 + qt * 64 + q) * 64 + dg * 16;
    #pragma unroll
    for (int v4 = 0; v4 < 4; ++v4) {
        float4 r;
        r.x = acc[v4 * 4 + 0] * inv; r.y = acc[v4 * 4 + 1] * inv;
        r.z = acc[v4 * 4 + 2] * inv; r.w = acc[v4 * 4 + 3] * inv;
        *(float4*)&orow[v4 * 4] = r;
    }
}

extern "C" void kernel_launch(void* const* d_in, const int* in_sizes, int n_in,
                              void* d_out, int out_size, void* d_ws, size_t ws_size,
                              hipStream_t stream)
{
    // setup_inputs order: x, Wk, Wq, Wv
    const float* x  = (const float*)d_in[0];
    const float* Wk = (const float*)d_in[1];
    const float* Wq = (const float*)d_in[2];
    const float* Wv = (const float*)d_in[3];
    float* outp = (float*)d_out;

    char* ws = (char*)d_ws;
    unsigned short* qbuf = (unsigned short*)(ws);                    // 2MB
    unsigned short* kbuf = (unsigned short*)(ws + 2*1024*1024);      // 2MB
    unsigned short* vtb  = (unsigned short*)(ws + 4*1024*1024);      // 2MB (V^T)
    unsigned short* wtb  = (unsigned short*)(ws + 6*1024*1024);      // 384KB (W^T)
    unsigned short* pO   = (unsigned short*)(ws + 7*1024*1024);      // 640*4096*2 = 5MB
    float*          pml  = (float*)(ws + 12*1024*1024 + 65536);      // 640*128*4 = 320KB

    wt_prep<<<dim3(16, 3), 256, 0, stream>>>(Wq, Wk, Wv, wtb);
    qkv_mfma<<<512, 256, 0, stream>>>(x, wtb, qbuf, kbuf, vtb);
    attn_mfma<<<640, 256, 0, stream>>>(qbuf, kbuf, vtb, pO, pml);
    attn_merge<<<256, 256, 0, stream>>>(pO, pml, outp);
}